// Round 1
// baseline (118.471 us; speedup 1.0000x reference)
//
#include <hip/hip_runtime.h>
#include <math.h>

#define HH 512
#define WW 512
#define NG 1000
#define STEP (1.0f / 511.0f)

// Derived per-gaussian params, 3 x float4 each (48 B):
//  [0] = px, py, cos, sin
//  [1] = isx, isy, cr, cg   (isx/isy include sqrt(0.5*log2e) so g = exp2(-(a^2+b^2)))
//  [2] = cb, 0, 0, 0
__global__ void gs_prep_kernel(const float* __restrict__ pos,
                               const float* __restrict__ sc,
                               const float* __restrict__ rot,
                               const float* __restrict__ col,
                               const float* __restrict__ op,
                               float4* __restrict__ params) {
    int g = blockIdx.x * blockDim.x + threadIdx.x;
    if (g >= NG) return;
    float px = pos[2 * g + 0];
    float py = pos[2 * g + 1];
    float sx = fabsf(sc[2 * g + 0]) + 1e-6f;
    float sy = fabsf(sc[2 * g + 1]) + 1e-6f;
    float r  = rot[g];
    float c  = cosf(r);
    float s  = sinf(r);
    float so = 1.0f / (1.0f + __expf(-op[g]));
    const float K = 0.84932180f;  // sqrt(0.5 * log2(e))
    float isx = K / sx;
    float isy = K / sy;
    float cr = so / (1.0f + __expf(-col[3 * g + 0]));
    float cg = so / (1.0f + __expf(-col[3 * g + 1]));
    float cb = so / (1.0f + __expf(-col[3 * g + 2]));
    params[3 * g + 0] = make_float4(px, py, c, s);
    params[3 * g + 1] = make_float4(isx, isy, cr, cg);
    params[3 * g + 2] = make_float4(cb, 0.0f, 0.0f, 0.0f);
}

__device__ __forceinline__ float clamp01(float v) {
    return fminf(fmaxf(v, 0.0f), 1.0f);
}

// One thread = 2 adjacent pixels in a row. Block 256 threads = one image row.
// Gaussian params are wave-uniform -> scalar (s_load) path.
__global__ __launch_bounds__(256) void gs_render_kernel(
        const float4* __restrict__ params, float* __restrict__ out) {
    const int row  = blockIdx.x;          // 0..511
    const int col0 = threadIdx.x * 2;     // 0..510 even
    const float y  = row * STEP;
    const float x0 = col0 * STEP;
    const float x1 = x0 + STEP;

    float accR0 = 0.0f, accG0 = 0.0f, accB0 = 0.0f;
    float accR1 = 0.0f, accG1 = 0.0f, accB1 = 0.0f;

#pragma unroll 4
    for (int g = 0; g < NG; ++g) {
        const float4 p0 = params[3 * g + 0];  // px py cos sin
        const float4 p1 = params[3 * g + 1];  // isx isy cr cg
        const float4 p2 = params[3 * g + 2];  // cb - - -

        const float dy  = y - p0.y;
        const float sdy = p0.w * dy;          // sin*dy
        const float cdy = p0.z * dy;          // cos*dy
        const float dx0 = x0 - p0.x;
        const float dx1 = x1 - p0.x;

        const float xr0 = fmaf(p0.z, dx0, sdy);   // cos*dx + sin*dy
        const float yr0 = fmaf(-p0.w, dx0, cdy);  // cos*dy - sin*dx
        const float xr1 = fmaf(p0.z, dx1, sdy);
        const float yr1 = fmaf(-p0.w, dx1, cdy);

        const float a0 = xr0 * p1.x;
        const float b0 = yr0 * p1.y;
        const float a1 = xr1 * p1.x;
        const float b1 = yr1 * p1.y;

        const float q0 = fmaf(a0, a0, b0 * b0);
        const float q1 = fmaf(a1, a1, b1 * b1);

        const float e0 = __builtin_amdgcn_exp2f(-q0);
        const float e1 = __builtin_amdgcn_exp2f(-q1);

        accR0 = fmaf(e0, p1.z, accR0);
        accG0 = fmaf(e0, p1.w, accG0);
        accB0 = fmaf(e0, p2.x, accB0);
        accR1 = fmaf(e1, p1.z, accR1);
        accG1 = fmaf(e1, p1.w, accG1);
        accB1 = fmaf(e1, p2.x, accB1);
    }

    const int base = row * WW + col0;
    const int hw = HH * WW;
    *reinterpret_cast<float2*>(&out[0 * hw + base]) =
        make_float2(clamp01(accR0), clamp01(accR1));
    *reinterpret_cast<float2*>(&out[1 * hw + base]) =
        make_float2(clamp01(accG0), clamp01(accG1));
    *reinterpret_cast<float2*>(&out[2 * hw + base]) =
        make_float2(clamp01(accB0), clamp01(accB1));
}

extern "C" void kernel_launch(void* const* d_in, const int* in_sizes, int n_in,
                              void* d_out, int out_size, void* d_ws, size_t ws_size,
                              hipStream_t stream) {
    const float* pos = (const float*)d_in[0];  // [1000,2]
    const float* sc  = (const float*)d_in[1];  // [1000,2]
    const float* rot = (const float*)d_in[2];  // [1000]
    const float* col = (const float*)d_in[3];  // [1000,3]
    const float* op  = (const float*)d_in[4];  // [1000]
    float* out = (float*)d_out;                // [3,512,512]
    float4* params = (float4*)d_ws;            // 1000*3*16 = 48 KB

    gs_prep_kernel<<<(NG + 255) / 256, 256, 0, stream>>>(pos, sc, rot, col, op, params);
    gs_render_kernel<<<HH, 256, 0, stream>>>(params, out);
}

// Round 2
// 89.832 us; speedup vs baseline: 1.3188x; 1.3188x over previous
//
#include <hip/hip_runtime.h>
#include <math.h>

#define HH 512
#define WW 512
#define NG 1000
#define STEP (1.0f / 511.0f)
#define HW3 (3 * HH * WW)
#define PARAMS_BYTES (48 * 1024)

// Derived per-gaussian params, 3 x float4 each (48 B):
//  [0] = px, py, rxx, rxy     (rxx = cos*K/sx, rxy = sin*K/sx)
//  [1] = ryx, ryy, cr, cg     (ryx = -sin*K/sy, ryy = cos*K/sy)
//  [2] = cb, 0, 0, 0
// with K = sqrt(0.5*log2(e)) folded in so g = exp2(-(a^2+b^2)).
__global__ void gs_prep(const float* __restrict__ pos,
                        const float* __restrict__ sc,
                        const float* __restrict__ rot,
                        const float* __restrict__ col,
                        const float* __restrict__ op,
                        float4* __restrict__ params) {
    int g = blockIdx.x * blockDim.x + threadIdx.x;
    if (g >= NG) return;
    float px = pos[2 * g + 0];
    float py = pos[2 * g + 1];
    float sx = fabsf(sc[2 * g + 0]) + 1e-6f;
    float sy = fabsf(sc[2 * g + 1]) + 1e-6f;
    float r  = rot[g];
    float c  = cosf(r);
    float s  = sinf(r);
    const float K = 0.84932180f;  // sqrt(0.5 * log2(e))
    float isx = K / sx;
    float isy = K / sy;
    float so = 1.0f / (1.0f + __expf(-op[g]));
    float cr = so / (1.0f + __expf(-col[3 * g + 0]));
    float cg = so / (1.0f + __expf(-col[3 * g + 1]));
    float cb = so / (1.0f + __expf(-col[3 * g + 2]));
    params[3 * g + 0] = make_float4(px, py, c * isx, s * isx);
    params[3 * g + 1] = make_float4(-s * isy, c * isy, cr, cg);
    params[3 * g + 2] = make_float4(cb, 0.0f, 0.0f, 0.0f);
}

__device__ __forceinline__ float clamp01(float v) {
    return fminf(fmaxf(v, 0.0f), 1.0f);
}

// One thread = 2 adjacent pixels in a row. blockIdx.x = row,
// blockIdx.y = gaussian-split slice s in [0,S). Slice 0 writes its partial
// to `out`, slice s>0 to wspart + (s-1)*HW3. Unclamped partial sums;
// gs_combine adds + clamps.
__global__ __launch_bounds__(256) void gs_render(
        const float4* __restrict__ params,
        float* __restrict__ out,
        float* __restrict__ wspart,
        int S) {
    const int row  = blockIdx.x;          // 0..511
    const int s    = blockIdx.y;          // 0..S-1
    const int col0 = threadIdx.x * 2;     // 0..510 even
    const float y  = row * STEP;
    const float x0 = col0 * STEP;

    const int g0 = (s * NG) / S;
    const int g1 = ((s + 1) * NG) / S;

    float aR0 = 0.0f, aG0 = 0.0f, aB0 = 0.0f;
    float aR1 = 0.0f, aG1 = 0.0f, aB1 = 0.0f;

#pragma unroll 2
    for (int g = g0; g < g1; ++g) {
        const float4 p0 = params[3 * g + 0];  // px py rxx rxy
        const float4 p1 = params[3 * g + 1];  // ryx ryy cr cg
        const float4 p2 = params[3 * g + 2];  // cb - - -

        const float dy  = y - p0.y;
        const float u   = p0.w * dy;          // rxy*dy
        const float v   = p1.y * dy;          // ryy*dy
        const float dx0 = x0 - p0.x;
        const float dx1 = dx0 + STEP;

        const float a0 = fmaf(p0.z, dx0, u);
        const float b0 = fmaf(p1.x, dx0, v);
        const float a1 = fmaf(p0.z, dx1, u);
        const float b1 = fmaf(p1.x, dx1, v);

        const float q0 = fmaf(a0, a0, b0 * b0);
        const float q1 = fmaf(a1, a1, b1 * b1);

        const float e0 = __builtin_amdgcn_exp2f(-q0);
        const float e1 = __builtin_amdgcn_exp2f(-q1);

        aR0 = fmaf(e0, p1.z, aR0);
        aG0 = fmaf(e0, p1.w, aG0);
        aB0 = fmaf(e0, p2.x, aB0);
        aR1 = fmaf(e1, p1.z, aR1);
        aG1 = fmaf(e1, p1.w, aG1);
        aB1 = fmaf(e1, p2.x, aB1);
    }

    float* dst = (s == 0) ? out : (wspart + (size_t)(s - 1) * HW3);
    const int base = row * WW + col0;
    const int hw = HH * WW;
    *reinterpret_cast<float2*>(&dst[0 * hw + base]) = make_float2(aR0, aR1);
    *reinterpret_cast<float2*>(&dst[1 * hw + base]) = make_float2(aG0, aG1);
    *reinterpret_cast<float2*>(&dst[2 * hw + base]) = make_float2(aB0, aB1);
}

// out = clamp01(out + sum of (S-1) ws partials), float4-vectorized.
__global__ __launch_bounds__(256) void gs_combine(
        float* __restrict__ out, const float* __restrict__ wspart, int S) {
    const int i = (blockIdx.x * blockDim.x + threadIdx.x) * 4;
    float4 v = *reinterpret_cast<float4*>(&out[i]);
    for (int k = 0; k < S - 1; ++k) {
        const float4 w = *reinterpret_cast<const float4*>(&wspart[(size_t)k * HW3 + i]);
        v.x += w.x; v.y += w.y; v.z += w.z; v.w += w.w;
    }
    v.x = clamp01(v.x);
    v.y = clamp01(v.y);
    v.z = clamp01(v.z);
    v.w = clamp01(v.w);
    *reinterpret_cast<float4*>(&out[i]) = v;
}

extern "C" void kernel_launch(void* const* d_in, const int* in_sizes, int n_in,
                              void* d_out, int out_size, void* d_ws, size_t ws_size,
                              hipStream_t stream) {
    const float* pos = (const float*)d_in[0];  // [1000,2]
    const float* sc  = (const float*)d_in[1];  // [1000,2]
    const float* rot = (const float*)d_in[2];  // [1000]
    const float* col = (const float*)d_in[3];  // [1000,3]
    const float* op  = (const float*)d_in[4];  // [1000]
    float* out = (float*)d_out;                // [3,512,512]

    float4* params = (float4*)d_ws;                          // 48 KB
    float*  parts  = (float*)((char*)d_ws + PARAMS_BYTES);   // (S-1) x 3 MB partials

    // Pick gaussian-split factor S (1..4) from available workspace.
    const size_t per = (size_t)HW3 * sizeof(float);
    size_t extra = 0;
    if (ws_size > PARAMS_BYTES) {
        extra = (ws_size - PARAMS_BYTES) / per;
        if (extra > 3) extra = 3;
    }
    const int S = 1 + (int)extra;

    gs_prep<<<(NG + 255) / 256, 256, 0, stream>>>(pos, sc, rot, col, op, params);
    gs_render<<<dim3(HH, S), 256, 0, stream>>>(params, out, parts, S);
    gs_combine<<<HW3 / 4 / 256, 256, 0, stream>>>(out, parts, S);
}

// Round 4
// 88.672 us; speedup vs baseline: 1.3361x; 1.0131x over previous
//
#include <hip/hip_runtime.h>
#include <math.h>

#define HH 512
#define WW 512
#define NG 1000
#define NPAIR (NG / 2)
#define STEP (1.0f / 511.0f)
#define HW3 (3 * HH * WW)
#define PARAMS_BYTES (48 * 1024)
#define MAX_S 8

typedef __fp16 half2v __attribute__((ext_vector_type(2)));

union F2H {
    float f;
    half2v h;
    unsigned int u;
};

// Per-PAIR params, 4 x float4 (64 B), gaussians g0=2p, g1=2p+1:
//  [0] = px0, py0, rxx0, rxy0
//  [1] = ryx0, ryy0, px1, py1
//  [2] = rxx1, rxy1, ryx1, ryy1
//  [3] = crpk, cgpk, cbpk, 0      (half2 pairs (c_g0, c_g1) as float bits)
// r** include K = sqrt(0.5*log2(e)) so g = exp2(-(a^2+b^2)).
__global__ void gs_prep(const float* __restrict__ pos,
                        const float* __restrict__ sc,
                        const float* __restrict__ rot,
                        const float* __restrict__ col,
                        const float* __restrict__ op,
                        float4* __restrict__ params) {
    int p = blockIdx.x * blockDim.x + threadIdx.x;
    if (p >= NPAIR) return;
    const float K = 0.84932180f;  // sqrt(0.5 * log2(e))

    float px[2], py[2], rxx[2], rxy[2], ryx[2], ryy[2], cr[2], cg[2], cb[2];
#pragma unroll
    for (int j = 0; j < 2; ++j) {
        int g = 2 * p + j;
        px[j] = pos[2 * g + 0];
        py[j] = pos[2 * g + 1];
        float sx = fabsf(sc[2 * g + 0]) + 1e-6f;
        float sy = fabsf(sc[2 * g + 1]) + 1e-6f;
        float r = rot[g];
        float c = cosf(r);
        float s = sinf(r);
        float isx = K / sx;
        float isy = K / sy;
        rxx[j] = c * isx;
        rxy[j] = s * isx;
        ryx[j] = -s * isy;
        ryy[j] = c * isy;
        float so = 1.0f / (1.0f + __expf(-op[g]));
        cr[j] = so / (1.0f + __expf(-col[3 * g + 0]));
        cg[j] = so / (1.0f + __expf(-col[3 * g + 1]));
        cb[j] = so / (1.0f + __expf(-col[3 * g + 2]));
    }
    F2H fr, fg, fb;
    fr.h = half2v{(__fp16)cr[0], (__fp16)cr[1]};
    fg.h = half2v{(__fp16)cg[0], (__fp16)cg[1]};
    fb.h = half2v{(__fp16)cb[0], (__fp16)cb[1]};

    params[4 * p + 0] = make_float4(px[0], py[0], rxx[0], rxy[0]);
    params[4 * p + 1] = make_float4(ryx[0], ryy[0], px[1], py[1]);
    params[4 * p + 2] = make_float4(rxx[1], rxy[1], ryx[1], ryy[1]);
    params[4 * p + 3] = make_float4(fr.f, fg.f, fb.f, 0.0f);
}

__device__ __forceinline__ float clamp01(float v) {
    return fminf(fmaxf(v, 0.0f), 1.0f);
}

// One thread = 4 adjacent pixels in a row. Block 256 = 2 rows x 128 threads.
// blockIdx.x = row-pair, blockIdx.y = gaussian-pair slice s in [0,S).
// Slice 0 -> out, slice s>0 -> wspart + (s-1)*HW3 (unclamped partials).
__global__ __launch_bounds__(256) void gs_render(
        const float4* __restrict__ params,
        float* __restrict__ out,
        float* __restrict__ wspart,
        int S) {
    const int tid  = threadIdx.x;
    const int row  = blockIdx.x * 2 + (tid >> 7);
    const int px0  = (tid & 127) * 4;
    const int s    = blockIdx.y;

    const float y  = row * STEP;
    const float x0 = px0 * STEP;
    const float x1 = x0 + STEP;
    const float x2 = x1 + STEP;
    const float x3 = x2 + STEP;

    const int p0 = (s * NPAIR) / S;
    const int p1 = ((s + 1) * NPAIR) / S;

    float aR0 = 0.f, aR1 = 0.f, aR2 = 0.f, aR3 = 0.f;
    float aG0 = 0.f, aG1 = 0.f, aG2 = 0.f, aG3 = 0.f;
    float aB0 = 0.f, aB1 = 0.f, aB2 = 0.f, aB3 = 0.f;

#pragma unroll 2
    for (int p = p0; p < p1; ++p) {
        const float4 q0 = params[4 * p + 0];  // px0 py0 rxx0 rxy0
        const float4 q1 = params[4 * p + 1];  // ryx0 ryy0 px1 py1
        const float4 q2 = params[4 * p + 2];  // rxx1 rxy1 ryx1 ryy1
        const float4 q3 = params[4 * p + 3];  // crpk cgpk cbpk -

        // gaussian 0
        const float dy0 = y - q0.y;
        const float u0  = q0.w * dy0;
        const float v0  = q1.y * dy0;
        const float A0  = fmaf(-q0.x, q0.z, u0);   // u0 - rxx0*px0
        const float B0  = fmaf(-q0.x, q1.x, v0);   // v0 - ryx0*px0
        const float a00 = fmaf(q0.z, x0, A0);
        const float a01 = fmaf(q0.z, x1, A0);
        const float a02 = fmaf(q0.z, x2, A0);
        const float a03 = fmaf(q0.z, x3, A0);
        const float b00 = fmaf(q1.x, x0, B0);
        const float b01 = fmaf(q1.x, x1, B0);
        const float b02 = fmaf(q1.x, x2, B0);
        const float b03 = fmaf(q1.x, x3, B0);
        const float e00 = __builtin_amdgcn_exp2f(-fmaf(a00, a00, b00 * b00));
        const float e01 = __builtin_amdgcn_exp2f(-fmaf(a01, a01, b01 * b01));
        const float e02 = __builtin_amdgcn_exp2f(-fmaf(a02, a02, b02 * b02));
        const float e03 = __builtin_amdgcn_exp2f(-fmaf(a03, a03, b03 * b03));

        // gaussian 1
        const float dy1 = y - q1.w;
        const float u1  = q2.y * dy1;
        const float v1  = q2.w * dy1;
        const float A1  = fmaf(-q1.z, q2.x, u1);
        const float B1  = fmaf(-q1.z, q2.z, v1);
        const float a10 = fmaf(q2.x, x0, A1);
        const float a11 = fmaf(q2.x, x1, A1);
        const float a12 = fmaf(q2.x, x2, A1);
        const float a13 = fmaf(q2.x, x3, A1);
        const float b10 = fmaf(q2.z, x0, B1);
        const float b11 = fmaf(q2.z, x1, B1);
        const float b12 = fmaf(q2.z, x2, B1);
        const float b13 = fmaf(q2.z, x3, B1);
        const float e10 = __builtin_amdgcn_exp2f(-fmaf(a10, a10, b10 * b10));
        const float e11 = __builtin_amdgcn_exp2f(-fmaf(a11, a11, b11 * b11));
        const float e12 = __builtin_amdgcn_exp2f(-fmaf(a12, a12, b12 * b12));
        const float e13 = __builtin_amdgcn_exp2f(-fmaf(a13, a13, b13 * b13));

        // pack per-pixel (e_g0, e_g1) pairs and dot2-accumulate
        const half2v pe0 = __builtin_amdgcn_cvt_pkrtz(e00, e10);
        const half2v pe1 = __builtin_amdgcn_cvt_pkrtz(e01, e11);
        const half2v pe2 = __builtin_amdgcn_cvt_pkrtz(e02, e12);
        const half2v pe3 = __builtin_amdgcn_cvt_pkrtz(e03, e13);

        F2H fr, fg, fb;
        fr.f = q3.x;
        fg.f = q3.y;
        fb.f = q3.z;

        aR0 = __builtin_amdgcn_fdot2(pe0, fr.h, aR0, false);
        aR1 = __builtin_amdgcn_fdot2(pe1, fr.h, aR1, false);
        aR2 = __builtin_amdgcn_fdot2(pe2, fr.h, aR2, false);
        aR3 = __builtin_amdgcn_fdot2(pe3, fr.h, aR3, false);
        aG0 = __builtin_amdgcn_fdot2(pe0, fg.h, aG0, false);
        aG1 = __builtin_amdgcn_fdot2(pe1, fg.h, aG1, false);
        aG2 = __builtin_amdgcn_fdot2(pe2, fg.h, aG2, false);
        aG3 = __builtin_amdgcn_fdot2(pe3, fg.h, aG3, false);
        aB0 = __builtin_amdgcn_fdot2(pe0, fb.h, aB0, false);
        aB1 = __builtin_amdgcn_fdot2(pe1, fb.h, aB1, false);
        aB2 = __builtin_amdgcn_fdot2(pe2, fb.h, aB2, false);
        aB3 = __builtin_amdgcn_fdot2(pe3, fb.h, aB3, false);
    }

    float* dst = (s == 0) ? out : (wspart + (size_t)(s - 1) * HW3);
    const int base = row * WW + px0;
    const int hw = HH * WW;
    *reinterpret_cast<float4*>(&dst[0 * hw + base]) = make_float4(aR0, aR1, aR2, aR3);
    *reinterpret_cast<float4*>(&dst[1 * hw + base]) = make_float4(aG0, aG1, aG2, aG3);
    *reinterpret_cast<float4*>(&dst[2 * hw + base]) = make_float4(aB0, aB1, aB2, aB3);
}

// out = clamp01(out + sum of (S-1) ws partials), float4-vectorized.
__global__ __launch_bounds__(256) void gs_combine(
        float* __restrict__ out, const float* __restrict__ wspart, int S) {
    const int i = (blockIdx.x * blockDim.x + threadIdx.x) * 4;
    float4 v = *reinterpret_cast<float4*>(&out[i]);
    for (int k = 0; k < S - 1; ++k) {
        const float4 w = *reinterpret_cast<const float4*>(&wspart[(size_t)k * HW3 + i]);
        v.x += w.x; v.y += w.y; v.z += w.z; v.w += w.w;
    }
    v.x = clamp01(v.x);
    v.y = clamp01(v.y);
    v.z = clamp01(v.z);
    v.w = clamp01(v.w);
    *reinterpret_cast<float4*>(&out[i]) = v;
}

extern "C" void kernel_launch(void* const* d_in, const int* in_sizes, int n_in,
                              void* d_out, int out_size, void* d_ws, size_t ws_size,
                              hipStream_t stream) {
    const float* pos = (const float*)d_in[0];  // [1000,2]
    const float* sc  = (const float*)d_in[1];  // [1000,2]
    const float* rot = (const float*)d_in[2];  // [1000]
    const float* col = (const float*)d_in[3];  // [1000,3]
    const float* op  = (const float*)d_in[4];  // [1000]
    float* out = (float*)d_out;                // [3,512,512]

    float4* params = (float4*)d_ws;                          // 500*64 B = 32 KB
    float*  parts  = (float*)((char*)d_ws + PARAMS_BYTES);   // (S-1) x 3 MB partials

    // Pick gaussian-split factor S (1..MAX_S) from available workspace.
    const size_t per = (size_t)HW3 * sizeof(float);
    size_t extra = 0;
    if (ws_size > PARAMS_BYTES) {
        extra = (ws_size - PARAMS_BYTES) / per;
        if (extra > MAX_S - 1) extra = MAX_S - 1;
    }
    const int S = 1 + (int)extra;

    gs_prep<<<(NPAIR + 255) / 256, 256, 0, stream>>>(pos, sc, rot, col, op, params);
    gs_render<<<dim3(HH / 2, S), 256, 0, stream>>>(params, out, parts, S);
    gs_combine<<<HW3 / 4 / 256, 256, 0, stream>>>(out, parts, S);
}